// Round 9
// baseline (480.705 us; speedup 1.0000x reference)
//
#include <hip/hip_runtime.h>
#include <hip/hip_bf16.h>

#define BSZ 4
#define SEQ 2048
#define DMODEL 1024
#define DINNER 2048
#define DSTATE 64
#define NH 32
#define HD 64
#define CKL 64            // chunk length
#define NCH 32            // chunks per sequence
#define CONVD 2176
#define DPROJ 4256
#define N1 4224           // GEMM1 N = DINNER + CONVD = 33*128 (dt cols handled separately)
#define MTOT 8192         // BSZ*SEQ
#define YSTR 72           // LDS row stride (bf16): 144 B, keeps 16B alignment

typedef __hip_bfloat16 bf16;
typedef __attribute__((ext_vector_type(8))) short short8;   // 8 bf16 (4 VGPRs)
typedef __attribute__((ext_vector_type(4))) short short4_;  // 8 bytes
typedef __attribute__((ext_vector_type(4))) float f32x4;

__device__ __forceinline__ float sigmoidf_(float x) { return 1.0f / (1.0f + __expf(-x)); }
__device__ __forceinline__ float bits2f(short s) { return __uint_as_float(((unsigned)(unsigned short)s) << 16); }
__device__ __forceinline__ short f2bits(float f) {
    bf16 h = __float2bfloat16(f);
    return *reinterpret_cast<short*>(&h);
}

__device__ __forceinline__ void gl_lds16(const bf16* g, bf16* l) {
    __builtin_amdgcn_global_load_lds((const __attribute__((address_space(1))) void*)g,
                                     (__attribute__((address_space(3))) void*)l, 16, 0, 0);
}

// L2 group swizzle: groups of 8 m-rows x all n-tiles get consecutive dispatch slots.
__device__ __forceinline__ void swz8(int& bx, int& by) {
    int nx = gridDim.x;
    int L = blockIdx.y * nx + blockIdx.x;
    int GSZ = nx * 8;
    int g = L / GSZ, r = L - g * GSZ;
    bx = r % nx;
    by = g * 8 + r / nx;
}

// ---------------- both weight converts in one launch ----------------
__global__ void k_cvt2(const float* __restrict__ W_in, const float* __restrict__ W_out,
                       const float* __restrict__ nw, bf16* __restrict__ win_b,
                       bf16* __restrict__ wout_b) {
    int g = (blockIdx.x * 256 + threadIdx.x) * 4;
    if (g < N1 * DMODEL) {
        f32x4 f = *(const f32x4*)&W_in[g];
        short4_ o;
#pragma unroll
        for (int j = 0; j < 4; j++) o[j] = f2bits(f[j]);
        *(short4_*)&win_b[g] = o;
    } else if (g < N1 * DMODEL + DMODEL * DINNER) {
        int g2 = g - N1 * DMODEL;
        f32x4 f = *(const f32x4*)&W_out[g2];
        f32x4 w = *(const f32x4*)&nw[g2 & (DINNER - 1)];
        short4_ o;
#pragma unroll
        for (int j = 0; j < 4; j++) o[j] = f2bits(f[j] * w[j]);
        *(short4_*)&wout_b[g2] = o;
    }
}

// ---------------- bf16 MFMA GEMM1: C[M][N](bf16) = A[M][K] * W[N][K]^T ----------
// 128x128 tile, BK=64, XOR-swizzled LDS (conflict-free), L2 group swizzle.
__global__ __launch_bounds__(256) void k_gemm_bt(const bf16* __restrict__ A, const bf16* __restrict__ W,
                                                 bf16* __restrict__ C, int N, int K, int lda) {
    __shared__ __align__(16) bf16 lA[128 * 64];
    __shared__ __align__(16) bf16 lB[128 * 64];
    const int tid = threadIdx.x;
    const int lane = tid & 63, w = tid >> 6;
    const int wm = w >> 1, wn = w & 1;
    const int lr = lane & 15, lk = lane >> 4;
    int bx, by;
    swz8(bx, by);
    const int m0 = by * 128, n0 = bx * 128;

    f32x4 acc[4][4];
#pragma unroll
    for (int i = 0; i < 4; i++)
#pragma unroll
        for (int j = 0; j < 4; j++) acc[i][j] = (f32x4){0.f, 0.f, 0.f, 0.f};

    const int r = tid >> 3;
    const int cs = ((tid & 7) ^ (r & 7)) * 8;
    const bf16* ga = A + (size_t)(m0 + r) * lda + cs;
    const bf16* gb = W + (size_t)(n0 + r) * K + cs;
    bf16* la0 = lA + tid * 8;
    bf16* lb0 = lB + tid * 8;
    const int sx = (lr & 7);

    for (int kt = 0; kt < K; kt += 64) {
#pragma unroll
        for (int i = 0; i < 4; i++) {
            gl_lds16(ga + kt + (size_t)(32 * i) * lda, la0 + 2048 * i);
            gl_lds16(gb + kt + (size_t)(32 * i) * K, lb0 + 2048 * i);
        }
        __syncthreads();
#pragma unroll
        for (int hh = 0; hh < 2; hh++) {
            const int cb = ((lk + 4 * hh) ^ sx) * 8;
            short8 af[4], bfr[4];
#pragma unroll
            for (int im = 0; im < 4; im++)
                af[im] = *(const short8*)&lA[(wm * 64 + im * 16 + lr) * 64 + cb];
#pragma unroll
            for (int jn = 0; jn < 4; jn++)
                bfr[jn] = *(const short8*)&lB[(wn * 64 + jn * 16 + lr) * 64 + cb];
#pragma unroll
            for (int im = 0; im < 4; im++)
#pragma unroll
                for (int jn = 0; jn < 4; jn++)
                    acc[im][jn] = __builtin_amdgcn_mfma_f32_16x16x32_bf16(af[im], bfr[jn], acc[im][jn], 0, 0, 0);
        }
        __syncthreads();
    }
#pragma unroll
    for (int im = 0; im < 4; im++) {
        int row = m0 + wm * 64 + im * 16 + lk * 4;
#pragma unroll
        for (int jn = 0; jn < 4; jn++) {
            int col = n0 + wn * 64 + jn * 16 + lr;
            bf16* cp = C + (size_t)row * N + col;
#pragma unroll
            for (int rr = 0; rr < 4; rr++) cp[(size_t)rr * N] = __float2bfloat16(acc[im][jn][rr]);
        }
    }
}

// ---------------- GEMM2 with fused RMSNorm (ssq accumulated from A-fragments) ----------------
// 128x64 tile -> 1024 blocks. A = gated y in zx (lda=N1, K=2048), W = wout_b (norm_w folded).
__global__ __launch_bounds__(256) void k_gemm2(const bf16* __restrict__ A, const bf16* __restrict__ W,
                                               float* __restrict__ C) {
    __shared__ __align__(16) bf16 lA[128 * 64];
    __shared__ __align__(16) bf16 lB[64 * 64];
    __shared__ float rsrow[128];
    const int tid = threadIdx.x;
    const int lane = tid & 63, w = tid >> 6;
    const int lr = lane & 15, lk = lane >> 4;
    int bx, by;
    swz8(bx, by);
    const int m0 = by * 128, n0 = bx * 64;
    const int K = DINNER, N = DMODEL;

    f32x4 acc[2][4];
#pragma unroll
    for (int i = 0; i < 2; i++)
#pragma unroll
        for (int j = 0; j < 4; j++) acc[i][j] = (f32x4){0.f, 0.f, 0.f, 0.f};
    float ssq[2] = {0.f, 0.f};

    const int r = tid >> 3;
    const int cs = ((tid & 7) ^ (r & 7)) * 8;
    const bf16* ga = A + (size_t)(m0 + r) * N1 + cs;
    const bf16* gb = W + (size_t)(n0 + r) * K + cs;
    bf16* la0 = lA + tid * 8;
    bf16* lb0 = lB + tid * 8;
    const int sx = (lr & 7);

    for (int kt = 0; kt < K; kt += 64) {
#pragma unroll
        for (int i = 0; i < 4; i++)
            gl_lds16(ga + kt + (size_t)(32 * i) * N1, la0 + 2048 * i);
#pragma unroll
        for (int i = 0; i < 2; i++)
            gl_lds16(gb + kt + (size_t)(32 * i) * K, lb0 + 2048 * i);
        __syncthreads();
#pragma unroll
        for (int hh = 0; hh < 2; hh++) {
            const int cb = ((lk + 4 * hh) ^ sx) * 8;
            short8 af[2], bfr[4];
#pragma unroll
            for (int im = 0; im < 2; im++) {
                af[im] = *(const short8*)&lA[(w * 32 + im * 16 + lr) * 64 + cb];
#pragma unroll
                for (int j = 0; j < 8; j++) { float v = bits2f(af[im][j]); ssq[im] += v * v; }
            }
#pragma unroll
            for (int jn = 0; jn < 4; jn++)
                bfr[jn] = *(const short8*)&lB[(jn * 16 + lr) * 64 + cb];
#pragma unroll
            for (int im = 0; im < 2; im++)
#pragma unroll
                for (int jn = 0; jn < 4; jn++)
                    acc[im][jn] = __builtin_amdgcn_mfma_f32_16x16x32_bf16(af[im], bfr[jn], acc[im][jn], 0, 0, 0);
        }
        __syncthreads();
    }
    // reduce ssq over the 4 lk lanes (A-frag row = w*32+im*16+lr)
#pragma unroll
    for (int im = 0; im < 2; im++) {
        float s = ssq[im];
        s += __shfl_down(s, 32);
        s += __shfl_down(s, 16);
        if (lane < 16) rsrow[w * 32 + im * 16 + lane] = rsqrtf(s * (1.0f / DINNER) + 1e-5f);
    }
    __syncthreads();
#pragma unroll
    for (int im = 0; im < 2; im++) {
        int rloc = w * 32 + im * 16 + lk * 4;
        int row = m0 + rloc;
#pragma unroll
        for (int rr = 0; rr < 4; rr++) {
            float s = rsrow[rloc + rr];
#pragma unroll
            for (int jn = 0; jn < 4; jn++) {
                int col = n0 + jn * 16 + lr;
                C[(size_t)(row + rr) * N + col] = acc[im][jn][rr] * s;
            }
        }
    }
}

// ---------------- fused: u row -> bf16 + dt projection (dt stored [h][t]) ----------------
__global__ __launch_bounds__(256) void k_prep(const float* __restrict__ u, const float* __restrict__ W_in,
                                              const float* __restrict__ dt_bias,
                                              bf16* __restrict__ u_b, float* __restrict__ dtt) {
    __shared__ __align__(16) float us[8 * DMODEL];
    const int t0 = blockIdx.x * 8;
    const int tid = threadIdx.x;
    const float* ur = u + (size_t)t0 * DMODEL;
    bf16* ub = u_b + (size_t)t0 * DMODEL;
#pragma unroll
    for (int i = 0; i < 8; i++) {
        int idx = (i * 256 + tid) * 4;
        f32x4 v = *(const f32x4*)&ur[idx];
        *(f32x4*)&us[idx] = v;
        short4_ o;
#pragma unroll
        for (int j = 0; j < 4; j++) o[j] = f2bits(v[j]);
        *(short4_*)&ub[idx] = o;
    }
    __syncthreads();
    const int h = tid >> 3, sub = tid & 7;
    const float* wr = W_in + (size_t)(DPROJ - NH + h) * DMODEL;
    float s[8] = {};
    for (int k = sub * 4; k < DMODEL; k += 32) {
        f32x4 w4 = *(const f32x4*)&wr[k];
#pragma unroll
        for (int rr = 0; rr < 8; rr++) {
            const float* up = &us[rr * DMODEL + k];
            s[rr] += up[0] * w4[0] + up[1] * w4[1] + up[2] * w4[2] + up[3] * w4[3];
        }
    }
#pragma unroll
    for (int rr = 0; rr < 8; rr++) {
        s[rr] += __shfl_down(s[rr], 4, 8);
        s[rr] += __shfl_down(s[rr], 2, 8);
        s[rr] += __shfl_down(s[rr], 1, 8);
    }
    if (sub == 0) {
        float bh = dt_bias[h];
#pragma unroll
        for (int rr = 0; rr < 8; rr++) {
            float x = s[rr] + bh;
            dtt[(size_t)h * MTOT + t0 + rr] = (x > 20.f) ? x : log1pf(__expf(x));
        }
    }
}

// ---------------- fused SSD scan with inline depthwise conv+SiLU ----------------
// Per (p-half, h, b) block, serial over 32 chunks. B/C/X tiles are produced by applying the
// 4-tap causal conv + SiLU in-register during chunk prefetch (weights preloaded in VGPRs;
// 1 wave/SIMD so VGPR budget is 512). Single barrier/chunk, parity double-buffered tiles.
__global__ __launch_bounds__(256, 1) void k_ssd(const float* __restrict__ cw, const float* __restrict__ cbias,
                                                const float* __restrict__ dtt, const float* __restrict__ A_log,
                                                const float* __restrict__ Dp, bf16* __restrict__ zx) {
    __shared__ __align__(16) short Ct[2][64 * YSTR];  // C [l][n]; own-wave rows reused as Y [l][p]
    __shared__ __align__(16) short Bt[2][64 * YSTR];  // B [s][n]
    __shared__ __align__(16) short Bn[2][64 * YSTR];  // B^T [n][l]
    __shared__ __align__(16) short Xt[2][32 * YSTR];  // X^T [p][l]
    __shared__ __align__(16) short Sb[2][32 * YSTR];  // state bf16 [p][n] at chunk start
    __shared__ __align__(16) short Gs[4 * 16 * YSTR]; // per-wave G
    __shared__ __align__(16) float Sf[32 * 68];       // running state fp32 [p][n]
    __shared__ __align__(16) float sdt2[2][64], sAc2[2][64], sf2[2][64];
    __shared__ float set2[2];

    const int ph = blockIdx.x, h = blockIdx.y, b = blockIdx.z;
    const int tid = threadIdx.x;
    const int lane = tid & 63, w = tid >> 6;
    const int lr = lane & 15, lk = lane >> 4;
    const float Ah = -__expf(A_log[h]);
    const float Dh = Dp[h];
    const int xcol = h * HD + ph * 32;   // z-col base AND conv-channel base of this block's X slice

    const int lrow = tid >> 2, c0 = (tid & 3) * 16, px = (tid & 3) * 8;
    const int zl = 16 * w + (lane >> 2), zp = (lane & 3) * 8;

    // preload conv weights/bias for this thread's 5 channel groups (kept in VGPRs)
    const int chb[5] = {2048 + c0, 2048 + c0 + 8, 2112 + c0, 2112 + c0 + 8, xcol + px};
    f32x4 cwv[5][8];
    float cbv[5][8];
#pragma unroll
    for (int r5 = 0; r5 < 5; r5++)
#pragma unroll
        for (int j = 0; j < 8; j++) {
            cwv[r5][j] = *(const f32x4*)&cw[(chb[r5] + j) * 4];
            cbv[r5][j] = cbias[chb[r5] + j];
        }

    auto conv8 = [&](const short* basep, int s, int r5) -> short8 {
        float a[8];
#pragma unroll
        for (int j = 0; j < 8; j++) a[j] = cbv[r5][j];
#pragma unroll
        for (int k = 0; k < 4; k++) {
            if (s + k >= 3) {   // causal zero-pad at sequence start
                short8 v = *(const short8*)(basep + (long)(k - 3) * N1);
#pragma unroll
                for (int j = 0; j < 8; j++) a[j] += bits2f(v[j]) * cwv[r5][j][k];
            }
        }
        short8 o;
#pragma unroll
        for (int j = 0; j < 8; j++) o[j] = f2bits(a[j] * sigmoidf_(a[j]));
        return o;
    };

    short8 rC0, rC1, rB0, rB1, rX, rZ;
    float rdt;
    auto load_chunk = [&](int cc) {
        int rows0 = b * SEQ + cc * CKL;
        int s = cc * CKL + lrow;   // seq position of this thread's row
        const short* zrow = (const short*)zx + (size_t)(rows0 + lrow) * N1 + DINNER;
        rB0 = conv8(zrow + 2048 + c0, s, 0);
        rB1 = conv8(zrow + 2048 + c0 + 8, s, 1);
        rC0 = conv8(zrow + 2112 + c0, s, 2);
        rC1 = conv8(zrow + 2112 + c0 + 8, s, 3);
        rX  = conv8(zrow + xcol + px, s, 4);
        rZ  = *(const short8*)((const short*)zx + (size_t)(rows0 + zl) * N1 + xcol + zp);
        rdt = dtt[(size_t)h * MTOT + rows0 + lane];
    };
    auto scatter = [&](int buf) {
        *(short8*)&Ct[buf][lrow * YSTR + c0] = rC0;
        *(short8*)&Ct[buf][lrow * YSTR + c0 + 8] = rC1;
        *(short8*)&Bt[buf][lrow * YSTR + c0] = rB0;
        *(short8*)&Bt[buf][lrow * YSTR + c0 + 8] = rB1;
#pragma unroll
        for (int j = 0; j < 8; j++) {
            Bn[buf][(c0 + j) * YSTR + lrow] = rB0[j];
            Bn[buf][(c0 + 8 + j) * YSTR + lrow] = rB1[j];
            Xt[buf][(px + j) * YSTR + lrow] = rX[j];
        }
    };
    auto dtscan = [&](int buf) {
        if (tid < 64) {
            float dv = rdt;
            float v = Ah * dv;
#pragma unroll
            for (int d = 1; d < 64; d <<= 1) { float o = __shfl_up(v, d); if (tid >= d) v += o; }
            float tot = __shfl(v, 63);
            sdt2[buf][tid] = dv; sAc2[buf][tid] = v; sf2[buf][tid] = __expf(tot - v) * dv;
            if (tid == 63) set2[buf] = __expf(tot);
        }
    };

    for (int i = tid; i < 32 * 68; i += 256) Sf[i] = 0.f;
    for (int i = tid; i < 32 * YSTR; i += 256) Sb[0][i] = 0;
    load_chunk(0);
    scatter(0);
    dtscan(0);
    __syncthreads();

    for (int c = 0; c < NCH; c++) {
        const int par = c & 1, nb = par ^ 1;
        const int rows0 = b * SEQ + c * CKL;
        float etot = set2[par];
        short8 zcur = rZ;                 // z of chunk c (loaded last iteration / pre-loop)
        if (c + 1 < NCH) load_chunk(c + 1);

        short8 cf0 = *(const short8*)&Ct[par][(16 * w + lr) * YSTR + lk * 8];
        short8 cf1 = *(const short8*)&Ct[par][(16 * w + lr) * YSTR + 32 + lk * 8];
        // P1: Y_off = C * S0^T
        f32x4 acc[2];
#pragma unroll
        for (int t = 0; t < 2; t++) {
            short8 s0 = *(const short8*)&Sb[par][(16 * t + lr) * YSTR + lk * 8];
            short8 s1 = *(const short8*)&Sb[par][(16 * t + lr) * YSTR + 32 + lk * 8];
            acc[t] = __builtin_amdgcn_mfma_f32_16x16x32_bf16(cf0, s0, (f32x4){0.f, 0.f, 0.f, 0.f}, 0, 0, 0);
            acc[t] = __builtin_amdgcn_mfma_f32_16x16x32_bf16(cf1, s1, acc[t], 0, 0, 0);
        }
        float sAcl[4], el[4];
#pragma unroll
        for (int rr = 0; rr < 4; rr++) { sAcl[rr] = sAc2[par][16 * w + lk * 4 + rr]; el[rr] = __expf(sAcl[rr]); }
#pragma unroll
        for (int t = 0; t < 2; t++)
#pragma unroll
            for (int rr = 0; rr < 4; rr++) acc[t][rr] *= el[rr];
        // P2: G = C * B^T, mask/decay, wave-private LDS round-trip
        short* gw = Gs + w * 16 * YSTR;
#pragma unroll
        for (int t = 0; t < 4; t++) {
            short8 b0 = *(const short8*)&Bt[par][(16 * t + lr) * YSTR + lk * 8];
            short8 b1 = *(const short8*)&Bt[par][(16 * t + lr) * YSTR + 32 + lk * 8];
            f32x4 g = __builtin_amdgcn_mfma_f32_16x16x32_bf16(cf0, b0, (f32x4){0.f, 0.f, 0.f, 0.f}, 0, 0, 0);
            g = __builtin_amdgcn_mfma_f32_16x16x32_bf16(cf1, b1, g, 0, 0, 0);
            int s = 16 * t + lr;
            float sAcs = sAc2[par][s], dts = sdt2[par][s];
#pragma unroll
            for (int rr = 0; rr < 4; rr++) {
                int l = 16 * w + lk * 4 + rr;
                float v = (s <= l) ? g[rr] * __expf(sAcl[rr] - sAcs) * dts : 0.f;
                gw[(lk * 4 + rr) * YSTR + s] = f2bits(v);
            }
        }
        // P3: Y += G * X
        short8 gf0 = *(const short8*)&gw[lr * YSTR + lk * 8];
        short8 gf1 = *(const short8*)&gw[lr * YSTR + 32 + lk * 8];
#pragma unroll
        for (int t = 0; t < 2; t++) {
            short8 x0 = *(const short8*)&Xt[par][(16 * t + lr) * YSTR + lk * 8];
            short8 x1 = *(const short8*)&Xt[par][(16 * t + lr) * YSTR + 32 + lk * 8];
            acc[t] = __builtin_amdgcn_mfma_f32_16x16x32_bf16(gf0, x0, acc[t], 0, 0, 0);
            acc[t] = __builtin_amdgcn_mfma_f32_16x16x32_bf16(gf1, x1, acc[t], 0, 0, 0);
        }
        // P4: Snew = (Xt*sf) * Bn^T ; Sf = Sf*etot + Snew ; Sb[nb] = bf16(Sf)
        {
            int pw = w & 1, nh2 = w >> 1;
            short8 xt0 = *(const short8*)&Xt[par][(16 * pw + lr) * YSTR + lk * 8];
            short8 xt1 = *(const short8*)&Xt[par][(16 * pw + lr) * YSTR + 32 + lk * 8];
            f32x4 sa0 = *(const f32x4*)&sf2[par][lk * 8];
            f32x4 sa1 = *(const f32x4*)&sf2[par][lk * 8 + 4];
            f32x4 sb0 = *(const f32x4*)&sf2[par][32 + lk * 8];
            f32x4 sb1 = *(const f32x4*)&sf2[par][32 + lk * 8 + 4];
            short8 xd0, xd1;
#pragma unroll
            for (int j = 0; j < 4; j++) {
                xd0[j]     = f2bits(bits2f(xt0[j])     * sa0[j]);
                xd0[4 + j] = f2bits(bits2f(xt0[4 + j]) * sa1[j]);
                xd1[j]     = f2bits(bits2f(xt1[j])     * sb0[j]);
                xd1[4 + j] = f2bits(bits2f(xt1[4 + j]) * sb1[j]);
            }
#pragma unroll
            for (int j = 0; j < 2; j++) {
                int nt = 2 * nh2 + j;
                short8 b0 = *(const short8*)&Bn[par][(16 * nt + lr) * YSTR + lk * 8];
                short8 b1 = *(const short8*)&Bn[par][(16 * nt + lr) * YSTR + 32 + lk * 8];
                f32x4 sacc = __builtin_amdgcn_mfma_f32_16x16x32_bf16(xd0, b0, (f32x4){0.f, 0.f, 0.f, 0.f}, 0, 0, 0);
                sacc = __builtin_amdgcn_mfma_f32_16x16x32_bf16(xd1, b1, sacc, 0, 0, 0);
#pragma unroll
                for (int rr = 0; rr < 4; rr++) {
                    int n = 16 * nt + lr;
                    int p = 16 * pw + lk * 4 + rr;
                    float nv = Sf[p * 68 + n] * etot + sacc[rr];
                    Sf[p * 68 + n] = nv;
                    Sb[nb][p * YSTR + n] = f2bits(nv);
                }
            }
        }
        // Y epilogue (+D*x) into Ct[par]'s own wave rows; coalesced z-gate
#pragma unroll
        for (int t = 0; t < 2; t++) {
#pragma unroll
            for (int rr = 0; rr < 4; rr++) {
                int p = 16 * t + lr;
                int l = 16 * w + lk * 4 + rr;
                float y = acc[t][rr] + Dh * bits2f(Xt[par][p * YSTR + l]);
                Ct[par][l * YSTR + p] = f2bits(y);
            }
        }
        {
            short8 y8 = *(const short8*)&Ct[par][zl * YSTR + zp];
            short* zpp = (short*)zx + (size_t)(rows0 + zl) * N1 + xcol + zp;
            short8 o;
#pragma unroll
            for (int j = 0; j < 8; j++) {
                float z = bits2f(zcur[j]);
                o[j] = f2bits(bits2f(y8[j]) * (z * sigmoidf_(z)));
            }
            *(short8*)zpp = o;
        }
        // stage chunk c+1 (off critical path: independent of this chunk's compute)
        if (c + 1 < NCH) {
            scatter(nb);
            dtscan(nb);
        }
        __syncthreads();
    }
}

extern "C" void kernel_launch(void* const* d_in, const int* in_sizes, int n_in,
                              void* d_out, int out_size, void* d_ws, size_t ws_size,
                              hipStream_t stream) {
    const float* u       = (const float*)d_in[0];
    const float* W_in    = (const float*)d_in[1];
    const float* conv_w  = (const float*)d_in[2];
    const float* conv_b  = (const float*)d_in[3];
    const float* dt_bias = (const float*)d_in[4];
    const float* A_log   = (const float*)d_in[5];
    const float* Dp      = (const float*)d_in[6];
    const float* norm_w  = (const float*)d_in[7];
    const float* W_out   = (const float*)d_in[8];
    float* out = (float*)d_out;

    // Workspace layout (~75 MiB total):
    char* ws = (char*)d_ws;
    bf16* zx     = (bf16*)ws;  ws += (size_t)MTOT * N1 * 2;       // 69.2 MB
    bf16* wout_b = (bf16*)ws;  ws += (size_t)DMODEL * DINNER * 2; // 4 MB
    float* dtt   = (float*)ws; ws += (size_t)NH * MTOT * 4;       // 1 MB, [h][t]

    // d_out (32 MiB) doubles as scratch for GEMM1 inputs only.
    bf16* u_b   = (bf16*)d_out;                                      // 16 MB
    bf16* win_b = (bf16*)((char*)d_out + (size_t)MTOT * DMODEL * 2); // 8.25 MB

    k_prep<<<MTOT / 8, 256, 0, stream>>>(u, W_in, dt_bias, u_b, dtt);
    k_cvt2<<<((N1 * DMODEL + DMODEL * DINNER) / 4 + 255) / 256, 256, 0, stream>>>(
        W_in, W_out, norm_w, win_b, wout_b);

    k_gemm_bt<<<dim3(N1 / 128, MTOT / 128), 256, 0, stream>>>(u_b, win_b, zx, N1, DMODEL, DMODEL);

    k_ssd<<<dim3(2, NH, BSZ), 256, 0, stream>>>(conv_w, conv_b, dtt, A_log, Dp, zx);

    k_gemm2<<<dim3(DMODEL / 64, MTOT / 128), 256, 0, stream>>>(zx, wout_b, out);
}

// Round 10
// 396.090 us; speedup vs baseline: 1.2136x; 1.2136x over previous
//
#include <hip/hip_runtime.h>
#include <hip/hip_bf16.h>

#define BSZ 4
#define SEQ 2048
#define DMODEL 1024
#define DINNER 2048
#define DSTATE 64
#define NH 32
#define HD 64
#define CKL 64            // chunk length
#define NCH 32            // chunks per sequence
#define CONVD 2176
#define DPROJ 4256
#define N1 4224           // GEMM1 N = DINNER + CONVD = 33*128 (dt cols handled separately)
#define MTOT 8192         // BSZ*SEQ
#define YSTR 72           // LDS row stride (bf16): 144 B, keeps 16B alignment

typedef __hip_bfloat16 bf16;
typedef __attribute__((ext_vector_type(8))) short short8;   // 8 bf16 (4 VGPRs)
typedef __attribute__((ext_vector_type(4))) short short4_;  // 8 bytes
typedef __attribute__((ext_vector_type(4))) float f32x4;

__device__ __forceinline__ float sigmoidf_(float x) { return 1.0f / (1.0f + __expf(-x)); }
__device__ __forceinline__ float bits2f(short s) { return __uint_as_float(((unsigned)(unsigned short)s) << 16); }
__device__ __forceinline__ short f2bits(float f) {
    bf16 h = __float2bfloat16(f);
    return *reinterpret_cast<short*>(&h);
}

__device__ __forceinline__ void gl_lds16(const bf16* g, bf16* l) {
    __builtin_amdgcn_global_load_lds((const __attribute__((address_space(1))) void*)g,
                                     (__attribute__((address_space(3))) void*)l, 16, 0, 0);
}

// L2 group swizzle: groups of 8 m-rows x all n-tiles get consecutive dispatch slots.
__device__ __forceinline__ void swz8(int& bx, int& by) {
    int nx = gridDim.x;
    int L = blockIdx.y * nx + blockIdx.x;
    int GSZ = nx * 8;
    int g = L / GSZ, r = L - g * GSZ;
    bx = r % nx;
    by = g * 8 + r / nx;
}

// ---------------- both weight converts in one launch ----------------
__global__ void k_cvt2(const float* __restrict__ W_in, const float* __restrict__ W_out,
                       const float* __restrict__ nw, bf16* __restrict__ win_b,
                       bf16* __restrict__ wout_b) {
    int g = (blockIdx.x * 256 + threadIdx.x) * 4;
    if (g < N1 * DMODEL) {
        f32x4 f = *(const f32x4*)&W_in[g];
        short4_ o;
#pragma unroll
        for (int j = 0; j < 4; j++) o[j] = f2bits(f[j]);
        *(short4_*)&win_b[g] = o;
    } else if (g < N1 * DMODEL + DMODEL * DINNER) {
        int g2 = g - N1 * DMODEL;
        f32x4 f = *(const f32x4*)&W_out[g2];
        f32x4 w = *(const f32x4*)&nw[g2 & (DINNER - 1)];
        short4_ o;
#pragma unroll
        for (int j = 0; j < 4; j++) o[j] = f2bits(f[j] * w[j]);
        *(short4_*)&wout_b[g2] = o;
    }
}

// ---------------- bf16 MFMA GEMM1: C[M][N](bf16) = A[M][K] * W[N][K]^T ----------
// 128x128 tile, BK=64, XOR-swizzled LDS (conflict-free), L2 group swizzle.
__global__ __launch_bounds__(256) void k_gemm_bt(const bf16* __restrict__ A, const bf16* __restrict__ W,
                                                 bf16* __restrict__ C, int N, int K, int lda) {
    __shared__ __align__(16) bf16 lA[128 * 64];
    __shared__ __align__(16) bf16 lB[128 * 64];
    const int tid = threadIdx.x;
    const int lane = tid & 63, w = tid >> 6;
    const int wm = w >> 1, wn = w & 1;
    const int lr = lane & 15, lk = lane >> 4;
    int bx, by;
    swz8(bx, by);
    const int m0 = by * 128, n0 = bx * 128;

    f32x4 acc[4][4];
#pragma unroll
    for (int i = 0; i < 4; i++)
#pragma unroll
        for (int j = 0; j < 4; j++) acc[i][j] = (f32x4){0.f, 0.f, 0.f, 0.f};

    const int r = tid >> 3;
    const int cs = ((tid & 7) ^ (r & 7)) * 8;
    const bf16* ga = A + (size_t)(m0 + r) * lda + cs;
    const bf16* gb = W + (size_t)(n0 + r) * K + cs;
    bf16* la0 = lA + tid * 8;
    bf16* lb0 = lB + tid * 8;
    const int sx = (lr & 7);

    for (int kt = 0; kt < K; kt += 64) {
#pragma unroll
        for (int i = 0; i < 4; i++) {
            gl_lds16(ga + kt + (size_t)(32 * i) * lda, la0 + 2048 * i);
            gl_lds16(gb + kt + (size_t)(32 * i) * K, lb0 + 2048 * i);
        }
        __syncthreads();
#pragma unroll
        for (int hh = 0; hh < 2; hh++) {
            const int cb = ((lk + 4 * hh) ^ sx) * 8;
            short8 af[4], bfr[4];
#pragma unroll
            for (int im = 0; im < 4; im++)
                af[im] = *(const short8*)&lA[(wm * 64 + im * 16 + lr) * 64 + cb];
#pragma unroll
            for (int jn = 0; jn < 4; jn++)
                bfr[jn] = *(const short8*)&lB[(wn * 64 + jn * 16 + lr) * 64 + cb];
#pragma unroll
            for (int im = 0; im < 4; im++)
#pragma unroll
                for (int jn = 0; jn < 4; jn++)
                    acc[im][jn] = __builtin_amdgcn_mfma_f32_16x16x32_bf16(af[im], bfr[jn], acc[im][jn], 0, 0, 0);
        }
        __syncthreads();
    }
#pragma unroll
    for (int im = 0; im < 4; im++) {
        int row = m0 + wm * 64 + im * 16 + lk * 4;
#pragma unroll
        for (int jn = 0; jn < 4; jn++) {
            int col = n0 + wn * 64 + jn * 16 + lr;
            bf16* cp = C + (size_t)row * N + col;
#pragma unroll
            for (int rr = 0; rr < 4; rr++) cp[(size_t)rr * N] = __float2bfloat16(acc[im][jn][rr]);
        }
    }
}

// ---------------- GEMM2 with fused RMSNorm: 128x128 tile, 512 blocks (2/CU) ----------------
// A = gated y in zx (lda=N1, K=2048), W = wout_b (norm_w folded). ssq from A-fragments;
// wn-duplicate waves compute/write identical rsrow values (benign).
__global__ __launch_bounds__(256) void k_gemm2(const bf16* __restrict__ A, const bf16* __restrict__ W,
                                               float* __restrict__ C) {
    __shared__ __align__(16) bf16 lA[128 * 64];
    __shared__ __align__(16) bf16 lB[128 * 64];
    __shared__ float rsrow[128];
    const int tid = threadIdx.x;
    const int lane = tid & 63, w = tid >> 6;
    const int wm = w >> 1, wn = w & 1;
    const int lr = lane & 15, lk = lane >> 4;
    int bx, by;
    swz8(bx, by);
    const int m0 = by * 128, n0 = bx * 128;
    const int K = DINNER, N = DMODEL;

    f32x4 acc[4][4];
#pragma unroll
    for (int i = 0; i < 4; i++)
#pragma unroll
        for (int j = 0; j < 4; j++) acc[i][j] = (f32x4){0.f, 0.f, 0.f, 0.f};
    float ssq[4] = {0.f, 0.f, 0.f, 0.f};

    const int r = tid >> 3;
    const int cs = ((tid & 7) ^ (r & 7)) * 8;
    const bf16* ga = A + (size_t)(m0 + r) * N1 + cs;
    const bf16* gb = W + (size_t)(n0 + r) * K + cs;
    bf16* la0 = lA + tid * 8;
    bf16* lb0 = lB + tid * 8;
    const int sx = (lr & 7);

    for (int kt = 0; kt < K; kt += 64) {
#pragma unroll
        for (int i = 0; i < 4; i++) {
            gl_lds16(ga + kt + (size_t)(32 * i) * N1, la0 + 2048 * i);
            gl_lds16(gb + kt + (size_t)(32 * i) * K, lb0 + 2048 * i);
        }
        __syncthreads();
#pragma unroll
        for (int hh = 0; hh < 2; hh++) {
            const int cb = ((lk + 4 * hh) ^ sx) * 8;
            short8 af[4], bfr[4];
#pragma unroll
            for (int im = 0; im < 4; im++) {
                af[im] = *(const short8*)&lA[(wm * 64 + im * 16 + lr) * 64 + cb];
#pragma unroll
                for (int j = 0; j < 8; j++) { float v = bits2f(af[im][j]); ssq[im] += v * v; }
            }
#pragma unroll
            for (int jn = 0; jn < 4; jn++)
                bfr[jn] = *(const short8*)&lB[(wn * 64 + jn * 16 + lr) * 64 + cb];
#pragma unroll
            for (int im = 0; im < 4; im++)
#pragma unroll
                for (int jn = 0; jn < 4; jn++)
                    acc[im][jn] = __builtin_amdgcn_mfma_f32_16x16x32_bf16(af[im], bfr[jn], acc[im][jn], 0, 0, 0);
        }
        __syncthreads();
    }
    // ssq reduce over the 4 lk lanes holding the same row (lr fixed)
#pragma unroll
    for (int im = 0; im < 4; im++) {
        float s = ssq[im];
        s += __shfl_down(s, 32);
        s += __shfl_down(s, 16);
        if (lane < 16) rsrow[wm * 64 + im * 16 + lane] = rsqrtf(s * (1.0f / DINNER) + 1e-5f);
    }
    __syncthreads();
#pragma unroll
    for (int im = 0; im < 4; im++) {
        int rloc = wm * 64 + im * 16 + lk * 4;
        int row = m0 + rloc;
#pragma unroll
        for (int rr = 0; rr < 4; rr++) {
            float s = rsrow[rloc + rr];
#pragma unroll
            for (int jn = 0; jn < 4; jn++) {
                int col = n0 + wn * 64 + jn * 16 + lr;
                C[(size_t)(row + rr) * N + col] = acc[im][jn][rr] * s;
            }
        }
    }
}

// ---------------- fused: u row -> bf16 + dt projection (dt stored [h][t]) ----------------
__global__ __launch_bounds__(256) void k_prep(const float* __restrict__ u, const float* __restrict__ W_in,
                                              const float* __restrict__ dt_bias,
                                              bf16* __restrict__ u_b, float* __restrict__ dtt) {
    __shared__ __align__(16) float us[8 * DMODEL];
    const int t0 = blockIdx.x * 8;
    const int tid = threadIdx.x;
    const float* ur = u + (size_t)t0 * DMODEL;
    bf16* ub = u_b + (size_t)t0 * DMODEL;
#pragma unroll
    for (int i = 0; i < 8; i++) {
        int idx = (i * 256 + tid) * 4;
        f32x4 v = *(const f32x4*)&ur[idx];
        *(f32x4*)&us[idx] = v;
        short4_ o;
#pragma unroll
        for (int j = 0; j < 4; j++) o[j] = f2bits(v[j]);
        *(short4_*)&ub[idx] = o;
    }
    __syncthreads();
    const int h = tid >> 3, sub = tid & 7;
    const float* wr = W_in + (size_t)(DPROJ - NH + h) * DMODEL;
    float s[8] = {};
    for (int k = sub * 4; k < DMODEL; k += 32) {
        f32x4 w4 = *(const f32x4*)&wr[k];
#pragma unroll
        for (int rr = 0; rr < 8; rr++) {
            const float* up = &us[rr * DMODEL + k];
            s[rr] += up[0] * w4[0] + up[1] * w4[1] + up[2] * w4[2] + up[3] * w4[3];
        }
    }
#pragma unroll
    for (int rr = 0; rr < 8; rr++) {
        s[rr] += __shfl_down(s[rr], 4, 8);
        s[rr] += __shfl_down(s[rr], 2, 8);
        s[rr] += __shfl_down(s[rr], 1, 8);
    }
    if (sub == 0) {
        float bh = dt_bias[h];
#pragma unroll
        for (int rr = 0; rr < 8; rr++) {
            float x = s[rr] + bh;
            dtt[(size_t)h * MTOT + t0 + rr] = (x > 20.f) ? x : log1pf(__expf(x));
        }
    }
}

// ---------------- depthwise causal conv (width 4) + bias + SiLU — 4 channels/thread ----------------
__global__ void k_conv(const bf16* __restrict__ zx, const float* __restrict__ cw,
                       const float* __restrict__ cb, bf16* __restrict__ xbc) {
    int g = (blockIdx.x * 256 + threadIdx.x) * 4;
    if (g >= MTOT * CONVD) return;
    int c0 = g % CONVD;
    int t = g / CONVD;
    int s = t & (SEQ - 1);
    const short* base = (const short*)(zx + (size_t)t * N1 + DINNER + c0);
    f32x4 w0 = *(const f32x4*)&cw[(c0 + 0) * 4];
    f32x4 w1 = *(const f32x4*)&cw[(c0 + 1) * 4];
    f32x4 w2 = *(const f32x4*)&cw[(c0 + 2) * 4];
    f32x4 w3 = *(const f32x4*)&cw[(c0 + 3) * 4];
    f32x4 a = *(const f32x4*)&cb[c0];
#pragma unroll
    for (int k = 0; k < 4; k++) {
        int st = s - 3 + k;
        if (st >= 0) {
            short4_ v = *(const short4_*)(base + (long)(k - 3) * N1);
            a[0] += bits2f(v[0]) * w0[k];
            a[1] += bits2f(v[1]) * w1[k];
            a[2] += bits2f(v[2]) * w2[k];
            a[3] += bits2f(v[3]) * w3[k];
        }
    }
    short4_ o;
#pragma unroll
    for (int j = 0; j < 4; j++) o[j] = f2bits(a[j] * sigmoidf_(a[j]));
    *(short4_*)&xbc[g] = o;
}

// ---------------- fused SSD scan: single barrier/chunk, parity double-buffered tiles ----------------
// Per (p-half, h, b) block, serial over 32 chunks. Scatter for chunk c+1 and the dt-scan for c+1
// execute during chunk c's compute; Sb (bf16 state) for c+1 is written by P4's epilogue.
__global__ __launch_bounds__(256) void k_ssd(const bf16* __restrict__ xbc, const float* __restrict__ dtt,
                                             const float* __restrict__ A_log, const float* __restrict__ Dp,
                                             bf16* __restrict__ zx) {
    __shared__ __align__(16) short Ct[2][64 * YSTR];  // C [l][n]; own-wave rows reused as Y [l][p]
    __shared__ __align__(16) short Bt[2][64 * YSTR];  // B [s][n]
    __shared__ __align__(16) short Bn[2][64 * YSTR];  // B^T [n][l]
    __shared__ __align__(16) short Xt[2][32 * YSTR];  // X^T [p][l]
    __shared__ __align__(16) short Sb[2][32 * YSTR];  // state bf16 [p][n] at chunk start
    __shared__ __align__(16) short Gs[4 * 16 * YSTR]; // per-wave G
    __shared__ __align__(16) float Sf[32 * 68];       // running state fp32 [p][n]
    __shared__ __align__(16) float sdt2[2][64], sAc2[2][64], sf2[2][64];
    __shared__ float set2[2];

    const int ph = blockIdx.x, h = blockIdx.y, b = blockIdx.z;
    const int tid = threadIdx.x;
    const int lane = tid & 63, w = tid >> 6;
    const int lr = lane & 15, lk = lane >> 4;
    const float Ah = -__expf(A_log[h]);
    const float Dh = Dp[h];
    const int xcol = h * HD + ph * 32;

    const int lrow = tid >> 2, c0 = (tid & 3) * 16, px = (tid & 3) * 8;
    const int zl = 16 * w + (lane >> 2), zp = (lane & 3) * 8;

    short8 rC0, rC1, rB0, rB1, rX, rZ;
    float rdt;
    auto load_chunk = [&](int cc) {
        int rows0 = b * SEQ + cc * CKL;
        const short* rp = (const short*)(xbc + (size_t)(rows0 + lrow) * CONVD);
        rC0 = *(const short8*)&rp[DINNER + DSTATE + c0];
        rC1 = *(const short8*)&rp[DINNER + DSTATE + c0 + 8];
        rB0 = *(const short8*)&rp[DINNER + c0];
        rB1 = *(const short8*)&rp[DINNER + c0 + 8];
        rX  = *(const short8*)&rp[xcol + px];
        rZ  = *(const short8*)((const short*)zx + (size_t)(rows0 + zl) * N1 + xcol + zp);
        rdt = dtt[(size_t)h * MTOT + rows0 + lane];
    };
    auto scatter = [&](int buf) {
        *(short8*)&Ct[buf][lrow * YSTR + c0] = rC0;
        *(short8*)&Ct[buf][lrow * YSTR + c0 + 8] = rC1;
        *(short8*)&Bt[buf][lrow * YSTR + c0] = rB0;
        *(short8*)&Bt[buf][lrow * YSTR + c0 + 8] = rB1;
#pragma unroll
        for (int j = 0; j < 8; j++) {
            Bn[buf][(c0 + j) * YSTR + lrow] = rB0[j];
            Bn[buf][(c0 + 8 + j) * YSTR + lrow] = rB1[j];
            Xt[buf][(px + j) * YSTR + lrow] = rX[j];
        }
    };
    auto dtscan = [&](int buf) {
        if (tid < 64) {
            float dv = rdt;
            float v = Ah * dv;
#pragma unroll
            for (int d = 1; d < 64; d <<= 1) { float o = __shfl_up(v, d); if (tid >= d) v += o; }
            float tot = __shfl(v, 63);
            sdt2[buf][tid] = dv; sAc2[buf][tid] = v; sf2[buf][tid] = __expf(tot - v) * dv;
            if (tid == 63) set2[buf] = __expf(tot);
        }
    };

    for (int i = tid; i < 32 * 68; i += 256) Sf[i] = 0.f;
    for (int i = tid; i < 32 * YSTR; i += 256) Sb[0][i] = 0;
    load_chunk(0);
    scatter(0);
    dtscan(0);
    __syncthreads();

    for (int c = 0; c < NCH; c++) {
        const int par = c & 1, nb = par ^ 1;
        const int rows0 = b * SEQ + c * CKL;
        float etot = set2[par];
        short8 zcur = rZ;                 // z of chunk c (loaded last iteration / pre-loop)
        if (c + 1 < NCH) load_chunk(c + 1);

        short8 cf0 = *(const short8*)&Ct[par][(16 * w + lr) * YSTR + lk * 8];
        short8 cf1 = *(const short8*)&Ct[par][(16 * w + lr) * YSTR + 32 + lk * 8];
        // P1: Y_off = C * S0^T
        f32x4 acc[2];
#pragma unroll
        for (int t = 0; t < 2; t++) {
            short8 s0 = *(const short8*)&Sb[par][(16 * t + lr) * YSTR + lk * 8];
            short8 s1 = *(const short8*)&Sb[par][(16 * t + lr) * YSTR + 32 + lk * 8];
            acc[t] = __builtin_amdgcn_mfma_f32_16x16x32_bf16(cf0, s0, (f32x4){0.f, 0.f, 0.f, 0.f}, 0, 0, 0);
            acc[t] = __builtin_amdgcn_mfma_f32_16x16x32_bf16(cf1, s1, acc[t], 0, 0, 0);
        }
        float sAcl[4], el[4];
#pragma unroll
        for (int rr = 0; rr < 4; rr++) { sAcl[rr] = sAc2[par][16 * w + lk * 4 + rr]; el[rr] = __expf(sAcl[rr]); }
#pragma unroll
        for (int t = 0; t < 2; t++)
#pragma unroll
            for (int rr = 0; rr < 4; rr++) acc[t][rr] *= el[rr];
        // P2: G = C * B^T, mask/decay, wave-private LDS round-trip
        short* gw = Gs + w * 16 * YSTR;
#pragma unroll
        for (int t = 0; t < 4; t++) {
            short8 b0 = *(const short8*)&Bt[par][(16 * t + lr) * YSTR + lk * 8];
            short8 b1 = *(const short8*)&Bt[par][(16 * t + lr) * YSTR + 32 + lk * 8];
            f32x4 g = __builtin_amdgcn_mfma_f32_16x16x32_bf16(cf0, b0, (f32x4){0.f, 0.f, 0.f, 0.f}, 0, 0, 0);
            g = __builtin_amdgcn_mfma_f32_16x16x32_bf16(cf1, b1, g, 0, 0, 0);
            int s = 16 * t + lr;
            float sAcs = sAc2[par][s], dts = sdt2[par][s];
#pragma unroll
            for (int rr = 0; rr < 4; rr++) {
                int l = 16 * w + lk * 4 + rr;
                float v = (s <= l) ? g[rr] * __expf(sAcl[rr] - sAcs) * dts : 0.f;
                gw[(lk * 4 + rr) * YSTR + s] = f2bits(v);
            }
        }
        // P3: Y += G * X
        short8 gf0 = *(const short8*)&gw[lr * YSTR + lk * 8];
        short8 gf1 = *(const short8*)&gw[lr * YSTR + 32 + lk * 8];
#pragma unroll
        for (int t = 0; t < 2; t++) {
            short8 x0 = *(const short8*)&Xt[par][(16 * t + lr) * YSTR + lk * 8];
            short8 x1 = *(const short8*)&Xt[par][(16 * t + lr) * YSTR + 32 + lk * 8];
            acc[t] = __builtin_amdgcn_mfma_f32_16x16x32_bf16(gf0, x0, acc[t], 0, 0, 0);
            acc[t] = __builtin_amdgcn_mfma_f32_16x16x32_bf16(gf1, x1, acc[t], 0, 0, 0);
        }
        // P4: Snew = (Xt*sf) * Bn^T ; Sf = Sf*etot + Snew ; Sb[nb] = bf16(Sf)
        {
            int pw = w & 1, nh2 = w >> 1;
            short8 xt0 = *(const short8*)&Xt[par][(16 * pw + lr) * YSTR + lk * 8];
            short8 xt1 = *(const short8*)&Xt[par][(16 * pw + lr) * YSTR + 32 + lk * 8];
            f32x4 sa0 = *(const f32x4*)&sf2[par][lk * 8];
            f32x4 sa1 = *(const f32x4*)&sf2[par][lk * 8 + 4];
            f32x4 sb0 = *(const f32x4*)&sf2[par][32 + lk * 8];
            f32x4 sb1 = *(const f32x4*)&sf2[par][32 + lk * 8 + 4];
            short8 xd0, xd1;
#pragma unroll
            for (int j = 0; j < 4; j++) {
                xd0[j]     = f2bits(bits2f(xt0[j])     * sa0[j]);
                xd0[4 + j] = f2bits(bits2f(xt0[4 + j]) * sa1[j]);
                xd1[j]     = f2bits(bits2f(xt1[j])     * sb0[j]);
                xd1[4 + j] = f2bits(bits2f(xt1[4 + j]) * sb1[j]);
            }
#pragma unroll
            for (int j = 0; j < 2; j++) {
                int nt = 2 * nh2 + j;
                short8 b0 = *(const short8*)&Bn[par][(16 * nt + lr) * YSTR + lk * 8];
                short8 b1 = *(const short8*)&Bn[par][(16 * nt + lr) * YSTR + 32 + lk * 8];
                f32x4 sacc = __builtin_amdgcn_mfma_f32_16x16x32_bf16(xd0, b0, (f32x4){0.f, 0.f, 0.f, 0.f}, 0, 0, 0);
                sacc = __builtin_amdgcn_mfma_f32_16x16x32_bf16(xd1, b1, sacc, 0, 0, 0);
#pragma unroll
                for (int rr = 0; rr < 4; rr++) {
                    int n = 16 * nt + lr;
                    int p = 16 * pw + lk * 4 + rr;
                    float nv = Sf[p * 68 + n] * etot + sacc[rr];
                    Sf[p * 68 + n] = nv;
                    Sb[nb][p * YSTR + n] = f2bits(nv);
                }
            }
        }
        // Y epilogue (+D*x) into Ct[par]'s own wave rows; coalesced z-gate
#pragma unroll
        for (int t = 0; t < 2; t++) {
#pragma unroll
            for (int rr = 0; rr < 4; rr++) {
                int p = 16 * t + lr;
                int l = 16 * w + lk * 4 + rr;
                float y = acc[t][rr] + Dh * bits2f(Xt[par][p * YSTR + l]);
                Ct[par][l * YSTR + p] = f2bits(y);
            }
        }
        {
            short8 y8 = *(const short8*)&Ct[par][zl * YSTR + zp];
            short* zpp = (short*)zx + (size_t)(rows0 + zl) * N1 + xcol + zp;
            short8 o;
#pragma unroll
            for (int j = 0; j < 8; j++) {
                float z = bits2f(zcur[j]);
                o[j] = f2bits(bits2f(y8[j]) * (z * sigmoidf_(z)));
            }
            *(short8*)zpp = o;
        }
        // stage chunk c+1 (off critical path: independent of this chunk's compute)
        if (c + 1 < NCH) {
            scatter(nb);
            dtscan(nb);
        }
        __syncthreads();
    }
}

extern "C" void kernel_launch(void* const* d_in, const int* in_sizes, int n_in,
                              void* d_out, int out_size, void* d_ws, size_t ws_size,
                              hipStream_t stream) {
    const float* u       = (const float*)d_in[0];
    const float* W_in    = (const float*)d_in[1];
    const float* conv_w  = (const float*)d_in[2];
    const float* conv_b  = (const float*)d_in[3];
    const float* dt_bias = (const float*)d_in[4];
    const float* A_log   = (const float*)d_in[5];
    const float* Dp      = (const float*)d_in[6];
    const float* norm_w  = (const float*)d_in[7];
    const float* W_out   = (const float*)d_in[8];
    float* out = (float*)d_out;

    // Workspace layout (~108 MiB total):
    char* ws = (char*)d_ws;
    bf16* zx     = (bf16*)ws;  ws += (size_t)MTOT * N1 * 2;       // 69.2 MB
    bf16* xbc    = (bf16*)ws;  ws += (size_t)MTOT * CONVD * 2;    // 34 MB
    bf16* wout_b = (bf16*)ws;  ws += (size_t)DMODEL * DINNER * 2; // 4 MB
    float* dtt   = (float*)ws; ws += (size_t)NH * MTOT * 4;       // 1 MB, [h][t]

    // d_out (32 MiB) doubles as scratch for GEMM1 inputs only.
    bf16* u_b   = (bf16*)d_out;                                      // 16 MB
    bf16* win_b = (bf16*)((char*)d_out + (size_t)MTOT * DMODEL * 2); // 8.25 MB

    k_prep<<<MTOT / 8, 256, 0, stream>>>(u, W_in, dt_bias, u_b, dtt);
    k_cvt2<<<((N1 * DMODEL + DMODEL * DINNER) / 4 + 255) / 256, 256, 0, stream>>>(
        W_in, W_out, norm_w, win_b, wout_b);

    k_gemm_bt<<<dim3(N1 / 128, MTOT / 128), 256, 0, stream>>>(u_b, win_b, zx, N1, DMODEL, DMODEL);

    k_conv<<<(MTOT * CONVD / 4 + 255) / 256, 256, 0, stream>>>(zx, conv_w, conv_b, xbc);

    k_ssd<<<dim3(2, NH, BSZ), 256, 0, stream>>>(xbc, dtt, A_log, Dp, zx);

    k_gemm2<<<dim3(DMODEL / 128, MTOT / 128), 256, 0, stream>>>(zx, wout_b, out);
}